// Round 1
// baseline (580.823 us; speedup 1.0000x reference)
//
#include <hip/hip_runtime.h>
#include <math.h>

#define NPIX  4194304          // 16*512*512
#define HW    262144           // 512*512
#define NCH   19
#define KSEL  262144u          // N_MIN
#define IGN   1
#define THRESH_F 0.35667494393873245f   // -log(0.7)

// ---------------------------------------------------------------------------
// Parallel "find bin containing kth largest" over an nbins (<=2048) histogram.
// Bins are value-monotone (higher bin = larger value). Finds B such that
// suffix_count(B) >= need && suffix_count(B+1) < need.
// res[0] = B, res[1] = suffix_count(B+1) (count strictly above bin B).
// Must be called by all 256 threads of the block.
// ---------------------------------------------------------------------------
__device__ void select_from_hist(const unsigned int* __restrict__ gh, int nbins,
                                 unsigned int need, int* res)
{
    __shared__ unsigned int sh[2048];
    __shared__ unsigned int ssum[256];
    const int tid = threadIdx.x;
    for (int i = tid; i < nbins; i += 256) sh[i] = gh[i];
    __syncthreads();
    const int per = nbins >> 8;
    const int base = tid * per;
    unsigned int p = 0;
    for (int i = 0; i < per; ++i) p += sh[base + i];
    ssum[tid] = p;
    __syncthreads();
    // suffix inclusive scan: ssum[t] = sum_{j>=t} part[j]
    for (int off = 1; off < 256; off <<= 1) {
        unsigned int add = (tid + off < 256) ? ssum[tid + off] : 0u;
        __syncthreads();
        ssum[tid] += add;
        __syncthreads();
    }
    unsigned int Sme   = ssum[tid];
    unsigned int Snext = (tid < 255) ? ssum[tid + 1] : 0u;
    if (Sme >= need && Snext < need) {
        unsigned int above = Snext;
        int bin = base;
        for (int b = base + per - 1; b >= base; --b) {
            unsigned int c = sh[b];
            if (above + c >= need) { bin = b; break; }
            above += c;
        }
        res[0] = bin; res[1] = (int)above;
    }
    if (tid == 0 && ssum[0] < need) { res[0] = 0; res[1] = 0; }  // degenerate guard
    __syncthreads();
}

__device__ __forceinline__ void block_sum_to_double(float v, double* target)
{
    #pragma unroll
    for (int o = 32; o > 0; o >>= 1) v += __shfl_down(v, o);
    __shared__ float wsum[4];
    int wid = threadIdx.x >> 6;
    if ((threadIdx.x & 63) == 0) wsum[wid] = v;
    __syncthreads();
    if (threadIdx.x == 0) {
        float t = wsum[0] + wsum[1] + wsum[2] + wsum[3];
        atomicAdd(target, (double)t);
    }
}

// ---------------------------------------------------------------------------
// K1: per-pixel CE loss, branch-1 accumulators, level-1 histogram (bits 31..21)
// ---------------------------------------------------------------------------
__global__ __launch_bounds__(256) void k_loss(
    const float* __restrict__ logits, const int* __restrict__ labels,
    float* __restrict__ losses, unsigned int* __restrict__ hist1,
    double* __restrict__ sum_gt, unsigned int* __restrict__ cnt_gt)
{
    __shared__ unsigned int lh[2048];
    for (int i = threadIdx.x; i < 2048; i += 256) lh[i] = 0u;
    __syncthreads();

    const int p0 = (blockIdx.x * 256 + threadIdx.x) * 4;   // grid exactly covers NPIX
    const int n  = p0 >> 18;          // / HW
    const int hw = p0 & (HW - 1);
    const float* base = logits + (size_t)n * (NCH * HW) + hw;

    float4 vals[NCH];
    #pragma unroll
    for (int c = 0; c < NCH; ++c)
        vals[c] = *(const float4*)(base + (size_t)c * HW);
    const int4 lab4 = *(const int4*)(labels + p0);
    const int labs[4] = {lab4.x, lab4.y, lab4.z, lab4.w};

    float lsum = 0.f;
    unsigned int lcnt = 0u;
    float out4[4];

    #pragma unroll
    for (int j = 0; j < 4; ++j) {
        float m = -__builtin_inff(), picked = 0.f;
        #pragma unroll
        for (int c = 0; c < NCH; ++c) {
            float x = (j == 0) ? vals[c].x : (j == 1) ? vals[c].y : (j == 2) ? vals[c].z : vals[c].w;
            m = fmaxf(m, x);
            if (c == labs[j]) picked = x;
        }
        float s = 0.f;
        #pragma unroll
        for (int c = 0; c < NCH; ++c) {
            float x = (j == 0) ? vals[c].x : (j == 1) ? vals[c].y : (j == 2) ? vals[c].z : vals[c].w;
            s += __expf(x - m);
        }
        float loss = m + logf(s) - picked;   // >= 0 by construction
        bool valid = (labs[j] != IGN);
        out4[j] = valid ? loss : -__builtin_inff();
        if (valid) {
            if (loss > THRESH_F) { lsum += loss; lcnt++; }
            atomicAdd(&lh[__float_as_uint(loss) >> 21], 1u);
        }
    }
    *(float4*)(losses + p0) = make_float4(out4[0], out4[1], out4[2], out4[3]);

    // branch-1 block reduction
    #pragma unroll
    for (int o = 32; o > 0; o >>= 1) { lsum += __shfl_down(lsum, o); lcnt += __shfl_down(lcnt, o); }
    __shared__ float  s_sum[4];
    __shared__ unsigned int s_cnt[4];
    int wid = threadIdx.x >> 6;
    if ((threadIdx.x & 63) == 0) { s_sum[wid] = lsum; s_cnt[wid] = lcnt; }
    __syncthreads();
    if (threadIdx.x == 0) {
        float t = s_sum[0] + s_sum[1] + s_sum[2] + s_sum[3];
        unsigned int tc = s_cnt[0] + s_cnt[1] + s_cnt[2] + s_cnt[3];
        atomicAdd(sum_gt, (double)t);
        atomicAdd(cnt_gt, tc);
    }
    // flush level-1 histogram
    for (int i = threadIdx.x; i < 2048; i += 256) {
        unsigned int c = lh[i];
        if (c) atomicAdd(&hist1[i], c);
    }
}

// ---------------------------------------------------------------------------
// K2: level-2 histogram (bits 20..10) restricted to selected level-1 bin,
//     plus sum of values strictly above level-1 bin.
// ---------------------------------------------------------------------------
__global__ __launch_bounds__(256) void k_hist2(
    const float* __restrict__ losses, const unsigned int* __restrict__ hist1,
    unsigned int* __restrict__ hist2, double* __restrict__ sum_hi1)
{
    __shared__ int res[2];
    select_from_hist(hist1, 2048, KSEL, res);
    const int B1 = res[0];

    __shared__ unsigned int lh[2048];
    for (int i = threadIdx.x; i < 2048; i += 256) lh[i] = 0u;
    __syncthreads();

    const int t = (blockIdx.x * 256 + threadIdx.x) * 4;
    const uint4 w4 = *(const uint4*)(losses + t);
    const unsigned int wv[4] = {w4.x, w4.y, w4.z, w4.w};
    float lsum = 0.f;
    #pragma unroll
    for (int j = 0; j < 4; ++j) {
        unsigned int w = wv[j];
        if (w & 0x80000000u) continue;          // invalid (-inf)
        int b1 = (int)(w >> 21);
        if (b1 == B1)      atomicAdd(&lh[(w >> 10) & 0x7FFu], 1u);
        else if (b1 > B1)  lsum += __uint_as_float(w);
    }
    __syncthreads();
    for (int i = threadIdx.x; i < 2048; i += 256)
        if (lh[i]) atomicAdd(&hist2[i], lh[i]);
    block_sum_to_double(lsum, sum_hi1);
}

// ---------------------------------------------------------------------------
// K3: level-3 histogram (bits 9..0) restricted to (B1,B2), plus sum of values
//     in B1 strictly above B2.
// ---------------------------------------------------------------------------
__global__ __launch_bounds__(256) void k_hist3(
    const float* __restrict__ losses, const unsigned int* __restrict__ hist1,
    const unsigned int* __restrict__ hist2, unsigned int* __restrict__ hist3,
    double* __restrict__ sum_hi2)
{
    __shared__ int res[2];
    select_from_hist(hist1, 2048, KSEL, res);
    const int B1 = res[0];
    const unsigned int a1 = (unsigned int)res[1];
    select_from_hist(hist2, 2048, KSEL - a1, res);
    const int B2 = res[0];

    __shared__ unsigned int lh[1024];
    for (int i = threadIdx.x; i < 1024; i += 256) lh[i] = 0u;
    __syncthreads();

    const int t = (blockIdx.x * 256 + threadIdx.x) * 4;
    const uint4 w4 = *(const uint4*)(losses + t);
    const unsigned int wv[4] = {w4.x, w4.y, w4.z, w4.w};
    float lsum = 0.f;
    #pragma unroll
    for (int j = 0; j < 4; ++j) {
        unsigned int w = wv[j];
        if (w & 0x80000000u) continue;
        if ((int)(w >> 21) != B1) continue;
        int b2 = (int)((w >> 10) & 0x7FFu);
        if (b2 == B2)      atomicAdd(&lh[w & 0x3FFu], 1u);
        else if (b2 > B2)  lsum += __uint_as_float(w);
    }
    __syncthreads();
    for (int i = threadIdx.x; i < 1024; i += 256)
        if (lh[i]) atomicAdd(&hist3[i], lh[i]);
    block_sum_to_double(lsum, sum_hi2);
}

// ---------------------------------------------------------------------------
// K4: final — exact kth value, mean_top, branch select, write scalar output.
// ---------------------------------------------------------------------------
__global__ __launch_bounds__(256) void k_final(
    const unsigned int* __restrict__ hist1, const unsigned int* __restrict__ hist2,
    const unsigned int* __restrict__ hist3,
    const double* __restrict__ sum_gt, const unsigned int* __restrict__ cnt_gt,
    const double* __restrict__ sum_hi1, const double* __restrict__ sum_hi2,
    float* __restrict__ out)
{
    __shared__ int res[2];
    select_from_hist(hist1, 2048, KSEL, res);
    const int B1 = res[0];
    const unsigned int a1 = (unsigned int)res[1];
    select_from_hist(hist2, 2048, KSEL - a1, res);
    const int B2 = res[0];
    const unsigned int a2 = (unsigned int)res[1];
    const unsigned int need3 = KSEL - a1 - a2;
    const unsigned int hibits = ((unsigned int)B1 << 21) | ((unsigned int)B2 << 10);

    // parallel scan of hist3 with value-weighted sums
    __shared__ unsigned int h3[1024];
    __shared__ unsigned int c_suf[256];
    __shared__ double s_suf[256];
    const int tid = threadIdx.x;
    for (int i = tid; i < 1024; i += 256) h3[i] = hist3[i];
    __syncthreads();
    unsigned int cp = 0; double sp = 0.0;
    for (int i = 0; i < 4; ++i) {
        int b = tid * 4 + i;
        unsigned int c = h3[b];
        cp += c;
        sp += (double)c * (double)__uint_as_float(hibits | (unsigned int)b);
    }
    c_suf[tid] = cp; s_suf[tid] = sp;
    __syncthreads();
    for (int off = 1; off < 256; off <<= 1) {
        unsigned int ca = (tid + off < 256) ? c_suf[tid + off] : 0u;
        double sa = (tid + off < 256) ? s_suf[tid + off] : 0.0;
        __syncthreads();
        c_suf[tid] += ca; s_suf[tid] += sa;
        __syncthreads();
    }
    __shared__ int r_l;
    __shared__ unsigned int r_above;
    __shared__ double r_sum3;
    unsigned int Sme   = c_suf[tid];
    unsigned int Snext = (tid < 255) ? c_suf[tid + 1] : 0u;
    double       Wnext = (tid < 255) ? s_suf[tid + 1] : 0.0;
    if (Sme >= need3 && Snext < need3) {
        unsigned int above = Snext;
        double sum3 = Wnext;
        int l = tid * 4;
        for (int b = tid * 4 + 3; b >= tid * 4; --b) {
            unsigned int c = h3[b];
            if (above + c >= need3) { l = b; break; }
            above += c;
            sum3 += (double)c * (double)__uint_as_float(hibits | (unsigned int)b);
        }
        r_l = l; r_above = above; r_sum3 = sum3;
    }
    if (tid == 0 && c_suf[0] < need3) { r_l = 0; r_above = 0; r_sum3 = 0.0; }
    __syncthreads();

    if (tid == 0) {
        float v = __uint_as_float(hibits | (unsigned int)r_l);   // exact kth value
        unsigned long long cnt_above = (unsigned long long)a1 + a2 + r_above;
        double sum_above = *sum_hi1 + *sum_hi2 + r_sum3;
        double mean_top = (sum_above + (double)(KSEL - cnt_above) * (double)v) / (double)KSEL;
        double result;
        if (v > THRESH_F) {
            unsigned int cg = *cnt_gt;
            result = *sum_gt / (double)(cg > 0u ? cg : 1u);
        } else {
            result = mean_top;
        }
        out[0] = (float)result;
    }
}

extern "C" void kernel_launch(void* const* d_in, const int* in_sizes, int n_in,
                              void* d_out, int out_size, void* d_ws, size_t ws_size,
                              hipStream_t stream)
{
    const float* logits = (const float*)d_in[0];
    const int*   labels = (const int*)d_in[1];
    float* out = (float*)d_out;

    // workspace layout
    unsigned int* hist1 = (unsigned int*)d_ws;            // 2048 u32
    unsigned int* hist2 = hist1 + 2048;                   // 2048 u32
    unsigned int* hist3 = hist2 + 2048;                   // 1024 u32  (ends at 20480 B)
    double* sum_gt  = (double*)((char*)d_ws + 20480);
    double* sum_hi1 = sum_gt + 1;
    double* sum_hi2 = sum_gt + 2;
    unsigned int* cnt_gt = (unsigned int*)(sum_gt + 3);   // at 20504
    float* losses = (float*)((char*)d_ws + 32768);        // 16 MiB

    hipMemsetAsync(d_ws, 0, 20512, stream);

    k_loss <<<dim3(NPIX / (256 * 4)), dim3(256), 0, stream>>>(logits, labels, losses, hist1, sum_gt, cnt_gt);
    k_hist2<<<dim3(NPIX / (256 * 4)), dim3(256), 0, stream>>>(losses, hist1, hist2, sum_hi1);
    k_hist3<<<dim3(NPIX / (256 * 4)), dim3(256), 0, stream>>>(losses, hist1, hist2, hist3, sum_hi2);
    k_final<<<dim3(1), dim3(256), 0, stream>>>(hist1, hist2, hist3, sum_gt, cnt_gt, sum_hi1, sum_hi2, out);
}

// Round 2
// 472.552 us; speedup vs baseline: 1.2291x; 1.2291x over previous
//
#include <hip/hip_runtime.h>
#include <math.h>

#define NPIX  4194304          // 16*512*512
#define HW    262144           // 512*512
#define NCH   19
#define KSEL  262144u          // N_MIN
#define IGN   1
#define THRESH_F 0.35667494393873245f   // -log(0.7)

#define P1BLK 4096             // K1 grid: 4096 blocks x 256 thr x 4 px
#define HBLK  256              // hist-pass grid
#define HTHR  65536            // HBLK*256

// ---------------------------------------------------------------------------
// Parallel "find bin containing kth largest" over an nbins (<=2048) histogram.
// res[0] = bin B, res[1] = count strictly above bin B.
// Must be called by all 256 threads of the block.
// ---------------------------------------------------------------------------
__device__ void select_from_hist(const unsigned int* __restrict__ gh, int nbins,
                                 unsigned int need, int* res)
{
    __shared__ unsigned int sh[2048];
    __shared__ unsigned int ssum[256];
    const int tid = threadIdx.x;
    for (int i = tid; i < nbins; i += 256) sh[i] = gh[i];
    __syncthreads();
    const int per = nbins >> 8;
    const int base = tid * per;
    unsigned int p = 0;
    for (int i = 0; i < per; ++i) p += sh[base + i];
    ssum[tid] = p;
    __syncthreads();
    for (int off = 1; off < 256; off <<= 1) {
        unsigned int add = (tid + off < 256) ? ssum[tid + off] : 0u;
        __syncthreads();
        ssum[tid] += add;
        __syncthreads();
    }
    unsigned int Sme   = ssum[tid];
    unsigned int Snext = (tid < 255) ? ssum[tid + 1] : 0u;
    if (Sme >= need && Snext < need) {
        unsigned int above = Snext;
        int bin = base;
        for (int b = base + per - 1; b >= base; --b) {
            unsigned int c = sh[b];
            if (above + c >= need) { bin = b; break; }
            above += c;
        }
        res[0] = bin; res[1] = (int)above;
    }
    if (tid == 0 && ssum[0] < need) { res[0] = 0; res[1] = 0; }
    __syncthreads();
}

// ---------------------------------------------------------------------------
// K1: per-pixel CE loss + per-block branch-1 partials. NO global atomics.
// ---------------------------------------------------------------------------
__global__ __launch_bounds__(256) void k_loss(
    const float* __restrict__ logits, const int* __restrict__ labels,
    float* __restrict__ losses,
    float* __restrict__ psum, unsigned int* __restrict__ pcnt)
{
    const int p0 = (blockIdx.x * 256 + threadIdx.x) * 4;   // grid exactly covers NPIX
    const int n  = p0 >> 18;          // / HW
    const int hw = p0 & (HW - 1);
    const float* base = logits + (size_t)n * (NCH * HW) + hw;

    float4 vals[NCH];
    #pragma unroll
    for (int c = 0; c < NCH; ++c)
        vals[c] = *(const float4*)(base + (size_t)c * HW);
    const int4 lab4 = *(const int4*)(labels + p0);
    const int labs[4] = {lab4.x, lab4.y, lab4.z, lab4.w};

    float lsum = 0.f;
    unsigned int lcnt = 0u;
    float out4[4];

    #pragma unroll
    for (int j = 0; j < 4; ++j) {
        float m = -__builtin_inff(), picked = 0.f;
        #pragma unroll
        for (int c = 0; c < NCH; ++c) {
            float x = (j == 0) ? vals[c].x : (j == 1) ? vals[c].y : (j == 2) ? vals[c].z : vals[c].w;
            m = fmaxf(m, x);
            if (c == labs[j]) picked = x;
        }
        float s = 0.f;
        #pragma unroll
        for (int c = 0; c < NCH; ++c) {
            float x = (j == 0) ? vals[c].x : (j == 1) ? vals[c].y : (j == 2) ? vals[c].z : vals[c].w;
            s += __expf(x - m);
        }
        float loss = m + logf(s) - picked;   // >= 0 by construction
        bool valid = (labs[j] != IGN);
        out4[j] = valid ? loss : -__builtin_inff();
        if (valid & (loss > THRESH_F)) { lsum += loss; lcnt++; }
    }
    *(float4*)(losses + p0) = make_float4(out4[0], out4[1], out4[2], out4[3]);

    // branch-1 block reduction -> per-block slot (no atomics)
    #pragma unroll
    for (int o = 32; o > 0; o >>= 1) { lsum += __shfl_down(lsum, o); lcnt += __shfl_down(lcnt, o); }
    __shared__ float  s_sum[4];
    __shared__ unsigned int s_cnt[4];
    int wid = threadIdx.x >> 6;
    if ((threadIdx.x & 63) == 0) { s_sum[wid] = lsum; s_cnt[wid] = lcnt; }
    __syncthreads();
    if (threadIdx.x == 0) {
        psum[blockIdx.x] = s_sum[0] + s_sum[1] + s_sum[2] + s_sum[3];
        pcnt[blockIdx.x] = s_cnt[0] + s_cnt[1] + s_cnt[2] + s_cnt[3];
    }
}

// ---------------------------------------------------------------------------
// K2: level-1 histogram (bits 31..21) over losses. 256 blocks, grid-stride.
// ---------------------------------------------------------------------------
__global__ __launch_bounds__(256) void k_hist1(
    const float* __restrict__ losses, unsigned int* __restrict__ hist1)
{
    __shared__ unsigned int lh[2048];
    for (int i = threadIdx.x; i < 2048; i += 256) lh[i] = 0u;
    __syncthreads();

    const uint4* l4 = (const uint4*)losses;
    for (int i = blockIdx.x * 256 + threadIdx.x; i < NPIX / 4; i += HTHR) {
        uint4 w4 = l4[i];
        const unsigned int wv[4] = {w4.x, w4.y, w4.z, w4.w};
        #pragma unroll
        for (int j = 0; j < 4; ++j) {
            unsigned int w = wv[j];
            if (!(w & 0x80000000u)) atomicAdd(&lh[w >> 21], 1u);
        }
    }
    __syncthreads();
    for (int i = threadIdx.x; i < 2048; i += 256) {
        unsigned int c = lh[i];
        if (c) atomicAdd(&hist1[i], c);
    }
}

// ---------------------------------------------------------------------------
// K3: level-2 histogram (bits 20..10) within B1 + per-block sum above B1.
// ---------------------------------------------------------------------------
__global__ __launch_bounds__(256) void k_hist2(
    const float* __restrict__ losses, const unsigned int* __restrict__ hist1,
    unsigned int* __restrict__ hist2, double* __restrict__ ghi1)
{
    __shared__ int res[2];
    select_from_hist(hist1, 2048, KSEL, res);
    const int B1 = res[0];

    __shared__ unsigned int lh[2048];
    for (int i = threadIdx.x; i < 2048; i += 256) lh[i] = 0u;
    __syncthreads();

    const uint4* l4 = (const uint4*)losses;
    float lsum = 0.f;
    for (int i = blockIdx.x * 256 + threadIdx.x; i < NPIX / 4; i += HTHR) {
        uint4 w4 = l4[i];
        const unsigned int wv[4] = {w4.x, w4.y, w4.z, w4.w};
        #pragma unroll
        for (int j = 0; j < 4; ++j) {
            unsigned int w = wv[j];
            if (w & 0x80000000u) continue;
            int b1 = (int)(w >> 21);
            if (b1 == B1)      atomicAdd(&lh[(w >> 10) & 0x7FFu], 1u);
            else if (b1 > B1)  lsum += __uint_as_float(w);
        }
    }
    __syncthreads();
    for (int i = threadIdx.x; i < 2048; i += 256)
        if (lh[i]) atomicAdd(&hist2[i], lh[i]);

    // per-block partial -> slot
    #pragma unroll
    for (int o = 32; o > 0; o >>= 1) lsum += __shfl_down(lsum, o);
    __shared__ float wsum[4];
    int wid = threadIdx.x >> 6;
    if ((threadIdx.x & 63) == 0) wsum[wid] = lsum;
    __syncthreads();
    if (threadIdx.x == 0)
        ghi1[blockIdx.x] = (double)(wsum[0] + wsum[1] + wsum[2] + wsum[3]);
}

// ---------------------------------------------------------------------------
// K4: level-3 histogram (bits 9..0) within (B1,B2) + per-block sum above B2.
// ---------------------------------------------------------------------------
__global__ __launch_bounds__(256) void k_hist3(
    const float* __restrict__ losses, const unsigned int* __restrict__ hist1,
    const unsigned int* __restrict__ hist2, unsigned int* __restrict__ hist3,
    double* __restrict__ ghi2)
{
    __shared__ int res[2];
    select_from_hist(hist1, 2048, KSEL, res);
    const int B1 = res[0];
    const unsigned int a1 = (unsigned int)res[1];
    select_from_hist(hist2, 2048, KSEL - a1, res);
    const int B2 = res[0];

    __shared__ unsigned int lh[1024];
    for (int i = threadIdx.x; i < 1024; i += 256) lh[i] = 0u;
    __syncthreads();

    const uint4* l4 = (const uint4*)losses;
    float lsum = 0.f;
    for (int i = blockIdx.x * 256 + threadIdx.x; i < NPIX / 4; i += HTHR) {
        uint4 w4 = l4[i];
        const unsigned int wv[4] = {w4.x, w4.y, w4.z, w4.w};
        #pragma unroll
        for (int j = 0; j < 4; ++j) {
            unsigned int w = wv[j];
            if (w & 0x80000000u) continue;
            if ((int)(w >> 21) != B1) continue;
            int b2 = (int)((w >> 10) & 0x7FFu);
            if (b2 == B2)      atomicAdd(&lh[w & 0x3FFu], 1u);
            else if (b2 > B2)  lsum += __uint_as_float(w);
        }
    }
    __syncthreads();
    for (int i = threadIdx.x; i < 1024; i += 256)
        if (lh[i]) atomicAdd(&hist3[i], lh[i]);

    #pragma unroll
    for (int o = 32; o > 0; o >>= 1) lsum += __shfl_down(lsum, o);
    __shared__ float wsum[4];
    int wid = threadIdx.x >> 6;
    if ((threadIdx.x & 63) == 0) wsum[wid] = lsum;
    __syncthreads();
    if (threadIdx.x == 0)
        ghi2[blockIdx.x] = (double)(wsum[0] + wsum[1] + wsum[2] + wsum[3]);
}

// ---------------------------------------------------------------------------
// K5: final — reduce partials, exact kth value, mean_top, branch, output.
// ---------------------------------------------------------------------------
__global__ __launch_bounds__(256) void k_final(
    const unsigned int* __restrict__ hist1, const unsigned int* __restrict__ hist2,
    const unsigned int* __restrict__ hist3,
    const float* __restrict__ psum, const unsigned int* __restrict__ pcnt,
    const double* __restrict__ ghi1, const double* __restrict__ ghi2,
    float* __restrict__ out)
{
    const int tid = threadIdx.x;

    // ---- reduce branch-1 partials (4096 each) + hi-sums (256 doubles each)
    double my_sum = 0.0;
    unsigned long long my_cnt = 0ull;
    #pragma unroll
    for (int i = 0; i < 16; ++i) {
        my_sum += (double)psum[tid * 16 + i];
        my_cnt += (unsigned long long)pcnt[tid * 16 + i];
    }
    double my_hi = ghi1[tid] + ghi2[tid] - ghi2[tid];  // ghi1 part
    double my_hi2 = ghi2[tid];
    #pragma unroll
    for (int o = 32; o > 0; o >>= 1) {
        my_sum += __shfl_down(my_sum, o);
        my_cnt += __shfl_down(my_cnt, o);
        my_hi  += __shfl_down(my_hi, o);
        my_hi2 += __shfl_down(my_hi2, o);
    }
    __shared__ double r_sumw[4], r_hiw[4], r_hi2w[4];
    __shared__ unsigned long long r_cntw[4];
    int wid = tid >> 6;
    if ((tid & 63) == 0) { r_sumw[wid] = my_sum; r_cntw[wid] = my_cnt; r_hiw[wid] = my_hi; r_hi2w[wid] = my_hi2; }
    __syncthreads();
    __shared__ double t_sum_gt, t_hi1, t_hi2;
    __shared__ unsigned long long t_cnt_gt;
    if (tid == 0) {
        t_sum_gt = r_sumw[0] + r_sumw[1] + r_sumw[2] + r_sumw[3];
        t_cnt_gt = r_cntw[0] + r_cntw[1] + r_cntw[2] + r_cntw[3];
        t_hi1    = r_hiw[0] + r_hiw[1] + r_hiw[2] + r_hiw[3];
        t_hi2    = r_hi2w[0] + r_hi2w[1] + r_hi2w[2] + r_hi2w[3];
    }
    __syncthreads();

    // ---- radix selection levels 1,2
    __shared__ int res[2];
    select_from_hist(hist1, 2048, KSEL, res);
    const int B1 = res[0];
    const unsigned int a1 = (unsigned int)res[1];
    select_from_hist(hist2, 2048, KSEL - a1, res);
    const int B2 = res[0];
    const unsigned int a2 = (unsigned int)res[1];
    const unsigned int need3 = KSEL - a1 - a2;
    const unsigned int hibits = ((unsigned int)B1 << 21) | ((unsigned int)B2 << 10);

    // ---- level-3 scan with value-weighted suffix sums
    __shared__ unsigned int h3[1024];
    __shared__ unsigned int c_suf[256];
    __shared__ double s_suf[256];
    for (int i = tid; i < 1024; i += 256) h3[i] = hist3[i];
    __syncthreads();
    unsigned int cp = 0; double sp = 0.0;
    #pragma unroll
    for (int i = 0; i < 4; ++i) {
        int b = tid * 4 + i;
        unsigned int c = h3[b];
        cp += c;
        sp += (double)c * (double)__uint_as_float(hibits | (unsigned int)b);
    }
    c_suf[tid] = cp; s_suf[tid] = sp;
    __syncthreads();
    for (int off = 1; off < 256; off <<= 1) {
        unsigned int ca = (tid + off < 256) ? c_suf[tid + off] : 0u;
        double sa = (tid + off < 256) ? s_suf[tid + off] : 0.0;
        __syncthreads();
        c_suf[tid] += ca; s_suf[tid] += sa;
        __syncthreads();
    }
    __shared__ int r_l;
    __shared__ unsigned int r_above;
    __shared__ double r_sum3;
    unsigned int Sme   = c_suf[tid];
    unsigned int Snext = (tid < 255) ? c_suf[tid + 1] : 0u;
    double       Wnext = (tid < 255) ? s_suf[tid + 1] : 0.0;
    if (Sme >= need3 && Snext < need3) {
        unsigned int above = Snext;
        double sum3 = Wnext;
        int l = tid * 4;
        for (int b = tid * 4 + 3; b >= tid * 4; --b) {
            unsigned int c = h3[b];
            if (above + c >= need3) { l = b; break; }
            above += c;
            sum3 += (double)c * (double)__uint_as_float(hibits | (unsigned int)b);
        }
        r_l = l; r_above = above; r_sum3 = sum3;
    }
    if (tid == 0 && c_suf[0] < need3) { r_l = 0; r_above = 0; r_sum3 = 0.0; }
    __syncthreads();

    if (tid == 0) {
        float v = __uint_as_float(hibits | (unsigned int)r_l);   // exact kth value
        unsigned long long cnt_above = (unsigned long long)a1 + a2 + r_above;
        double sum_above = t_hi1 + t_hi2 + r_sum3;
        double mean_top = (sum_above + (double)(KSEL - cnt_above) * (double)v) / (double)KSEL;
        double result;
        if (v > THRESH_F) {
            unsigned long long cg = t_cnt_gt;
            result = t_sum_gt / (double)(cg > 0ull ? cg : 1ull);
        } else {
            result = mean_top;
        }
        out[0] = (float)result;
    }
}

extern "C" void kernel_launch(void* const* d_in, const int* in_sizes, int n_in,
                              void* d_out, int out_size, void* d_ws, size_t ws_size,
                              hipStream_t stream)
{
    const float* logits = (const float*)d_in[0];
    const int*   labels = (const int*)d_in[1];
    float* out = (float*)d_out;

    // workspace layout (bytes)
    unsigned int* hist1 = (unsigned int*)d_ws;                     //     0 .. 8191
    unsigned int* hist2 = hist1 + 2048;                            //  8192 .. 16383
    unsigned int* hist3 = hist2 + 2048;                            // 16384 .. 20479
    float*        psum  = (float*)((char*)d_ws + 20480);           // 4096 f32
    unsigned int* pcnt  = (unsigned int*)((char*)d_ws + 36864);    // 4096 u32
    double*       ghi1  = (double*)((char*)d_ws + 53248);          // 256 f64
    double*       ghi2  = (double*)((char*)d_ws + 55296);          // 256 f64
    float*        losses = (float*)((char*)d_ws + 65536);          // 16 MiB

    hipMemsetAsync(d_ws, 0, 20480, stream);   // zero the three histograms only

    k_loss <<<dim3(P1BLK), dim3(256), 0, stream>>>(logits, labels, losses, psum, pcnt);
    k_hist1<<<dim3(HBLK),  dim3(256), 0, stream>>>(losses, hist1);
    k_hist2<<<dim3(HBLK),  dim3(256), 0, stream>>>(losses, hist1, hist2, ghi1);
    k_hist3<<<dim3(HBLK),  dim3(256), 0, stream>>>(losses, hist1, hist2, hist3, ghi2);
    k_final<<<dim3(1),     dim3(256), 0, stream>>>(hist1, hist2, hist3, psum, pcnt, ghi1, ghi2, out);
}